// Round 3
// baseline (268.796 us; speedup 1.0000x reference)
//
#include <hip/hip_runtime.h>

#define N_SERIES 1024
#define N_TIME 600
#define INPUT_SIZE 168
#define OUTPUT_SIZE 24
#define N_S 4
#define SEAS 24
#define N_WINDOWS (N_TIME - INPUT_SIZE - OUTPUT_SIZE + 1) /* 409 */
#define SEAS_LEN (N_TIME + SEAS)                          /* 624 */

#define INS_ELEMS (N_WINDOWS * N_SERIES * (INPUT_SIZE + N_S)) /* 72,036,352 */
#define OUTS_ELEMS (N_WINDOWS * N_SERIES * OUTPUT_SIZE)       /* 10,051,584 */
#define LEV_ELEMS (N_SERIES * N_TIME)
#define SEAS_ELEMS (N_SERIES * SEAS_LEN)

#define NQ_OUTS (OUTS_ELEMS / 4)          /* 2,512,896 */
#define NQ_STATIC (N_WINDOWS * N_SERIES)  /* 418,816 : one float4 per row */
#define NQ_COPY (NQ_OUTS + NQ_STATIC)
#define NQ_INS2 (N_WINDOWS * N_SERIES * 42) /* 17,590,272 : 42 float4 per row */

#define SCAN_BLOCKS 16
#define COPY_BLOCKS 2048

typedef float f4 __attribute__((ext_vector_type(4)));

// ---------------------------------------------------------------------------
// Kernel 1 (fused):
//   blocks [0,16): exponential-smoothing scan, 1 lane per series, with LDS
//     tile staging so all global accesses are coalesced 24-float runs instead
//     of 64-line scatters. Seasonal ring buffer in registers (indices are
//     compile-time: t % 24 == (u+1) % 24 inside each 24-step chunk).
//   blocks [16, ...): outsample copy + static s_matrix columns (independent
//     of the scan) — hidden under the scan's latency.
// ---------------------------------------------------------------------------
__global__ __launch_bounds__(64) void scan_copy_kernel(
    const float* __restrict__ y, const float* __restrict__ s_matrix,
    const float* __restrict__ embeds, const int* __restrict__ idxs,
    float* __restrict__ levels, float* __restrict__ seas1,
    f4* __restrict__ out_ins, f4* __restrict__ out_outs)
{
    __shared__ float buf_a[64][25]; // y tile, reused in-place as levels tile
    __shared__ float buf_b[64][25]; // seasonality tile

    if (blockIdx.x < SCAN_BLOCKS) {
        const int lane = threadIdx.x;
        const int s0 = blockIdx.x * 64;
        const int s = s0 + lane;
        const int row = idxs[s];
        const float* e = embeds + row * (2 + SEAS);

        const float lev_sms = 1.0f / (1.0f + __expf(-e[0]));
        const float seas_sms = 1.0f / (1.0f + __expf(-e[1]));
        const float one_m_lev = 1.0f - lev_sms;
        const float one_m_seas = 1.0f - seas_sms;

        float sb[SEAS];
#pragma unroll
        for (int j = 0; j < SEAS; ++j) {
            float v = __expf(e[2 + j]);
            sb[j] = v;
            buf_b[lane][j] = v;
        }
        __syncthreads();
        // coalesced write of init seasonality columns 0..23
#pragma unroll
        for (int k = 0; k < 24; ++k) {
            int i = lane + k * 64;
            int r = i / 24;
            int col = i - r * 24;
            seas1[(s0 + r) * SEAS_LEN + col] = buf_b[r][col];
        }
        // column 24 (= wrap of init_seas) and levels column 0: small scatters
        seas1[s * SEAS_LEN + SEAS] = sb[0];
        float lev = __fdividef(y[s * N_TIME], sb[0]);
        levels[s * N_TIME] = lev;
        __syncthreads();

        for (int c = 0; c < 25; ++c) {
            const int t0 = 1 + c * 24;
            const int cnt = (t0 + 24 <= N_TIME) ? 24 : (N_TIME - t0); // 24 or 23
            // cooperative coalesced load of y[s0..s0+63][t0..t0+cnt-1]
#pragma unroll
            for (int k = 0; k < 24; ++k) {
                int i = lane + k * 64;
                int r = i / 24;
                int col = i - r * 24;
                if (t0 + col < N_TIME)
                    buf_a[r][col] = y[(s0 + r) * N_TIME + t0 + col];
            }
            __syncthreads();
            // 24 recurrence steps; ring index (u+1)%24 is compile-time
#pragma unroll
            for (int u = 0; u < 24; ++u) {
                if (u < cnt) {
                    const int k = (u + 1) % 24;
                    float yt = buf_a[lane][u];
                    float st = sb[k];
                    float newlev =
                        lev_sms * __fdividef(yt, st) + one_m_lev * lev;
                    float news =
                        seas_sms * __fdividef(yt, newlev) + one_m_seas * st;
                    lev = newlev;
                    sb[k] = news;
                    buf_a[lane][u] = newlev; // overwrite y with level
                    buf_b[lane][u] = news;
                }
            }
            __syncthreads();
            // cooperative coalesced writes of levels / seasonalities
#pragma unroll
            for (int k = 0; k < 24; ++k) {
                int i = lane + k * 64;
                int r = i / 24;
                int col = i - r * 24;
                if (t0 + col < N_TIME) {
                    levels[(s0 + r) * N_TIME + t0 + col] = buf_a[r][col];
                    seas1[(s0 + r) * SEAS_LEN + SEAS + t0 + col] = buf_b[r][col];
                }
            }
            __syncthreads();
        }
    } else {
        // copy role: outsample windows + static s_matrix columns
        const f4* sm4 = (const f4*)s_matrix;
        int idx = (blockIdx.x - SCAN_BLOCKS) * 64 + threadIdx.x;
        const int stride = (gridDim.x - SCAN_BLOCKS) * 64;
        for (; idx < NQ_COPY; idx += stride) {
            if (idx < NQ_OUTS) {
                int rowq = idx / 6;
                int j4 = idx - rowq * 6;
                int w = rowq >> 10;
                int s = rowq & 1023;
                const float* yp = y + s * N_TIME + w + INPUT_SIZE + j4 * 4;
                f4 v = {yp[0], yp[1], yp[2], yp[3]};
                __builtin_nontemporal_store(v, &out_outs[idx]);
            } else {
                int j = idx - NQ_OUTS; // w*1024 + s
                int s = j & 1023;
                f4 v = sm4[s];
                __builtin_nontemporal_store(v, &out_ins[j * 43 + 42]);
            }
        }
    }
}

// ---------------------------------------------------------------------------
// Kernel 2: insample log-normalized windows (the 280 MB write stream).
// Nontemporal stores keep y/levels/seas resident in L2.
// ---------------------------------------------------------------------------
__global__ __launch_bounds__(256) void ins_kernel(
    const float* __restrict__ y, const float* __restrict__ levels,
    const float* __restrict__ seas1, f4* __restrict__ out_ins)
{
    const int stride = gridDim.x * blockDim.x;
    for (int q = blockIdx.x * blockDim.x + threadIdx.x; q < NQ_INS2;
         q += stride) {
        int rowq = q / 42;
        int e4 = q - rowq * 42;
        int w = rowq >> 10;
        int s = rowq & 1023;
        int t = w + e4 * 4;
        float lev = levels[s * N_TIME + w + INPUT_SIZE - 1];
        const float* yp = y + s * N_TIME + t;
        const float* sp = seas1 + s * SEAS_LEN + t;
        float vv[4];
#pragma unroll
        for (int j = 0; j < 4; ++j)
            vv[j] = __logf(__fdividef(yp[j], lev * sp[j]));
        f4 v = {vv[0], vv[1], vv[2], vv[3]};
        __builtin_nontemporal_store(v, &out_ins[rowq * 43 + e4]);
    }
}

extern "C" void kernel_launch(void* const* d_in, const int* in_sizes, int n_in,
                              void* d_out, int out_size, void* d_ws, size_t ws_size,
                              hipStream_t stream) {
    const float* y      = (const float*)d_in[0];
    const float* sm     = (const float*)d_in[1];
    const float* embeds = (const float*)d_in[2];
    const int*   idxs   = (const int*)d_in[3];

    float* out      = (float*)d_out;
    float* out_ins  = out;
    float* out_outs = out + INS_ELEMS;
    float* out_lev  = out + INS_ELEMS + OUTS_ELEMS;
    float* out_seas = out_lev + LEV_ELEMS;

    scan_copy_kernel<<<SCAN_BLOCKS + COPY_BLOCKS, 64, 0, stream>>>(
        y, sm, embeds, idxs, out_lev, out_seas, (f4*)out_ins,
        (f4*)out_outs);
    ins_kernel<<<2048, 256, 0, stream>>>(y, out_lev, out_seas,
                                         (f4*)out_ins);
}

// Round 4
// 181.337 us; speedup vs baseline: 1.4823x; 1.4823x over previous
//
#include <hip/hip_runtime.h>

#define N_SERIES 1024
#define N_TIME 600
#define INPUT_SIZE 168
#define OUTPUT_SIZE 24
#define N_S 4
#define SEAS 24
#define N_WINDOWS (N_TIME - INPUT_SIZE - OUTPUT_SIZE + 1) /* 409 */
#define SEAS_LEN (N_TIME + SEAS)                          /* 624 */

#define INS_ELEMS (N_WINDOWS * N_SERIES * (INPUT_SIZE + N_S)) /* 72,036,352 */
#define OUTS_ELEMS (N_WINDOWS * N_SERIES * OUTPUT_SIZE)       /* 10,051,584 */
#define LEV_ELEMS (N_SERIES * N_TIME)
#define SEAS_ELEMS (N_SERIES * SEAS_LEN)

#define NQ_OUTS (OUTS_ELEMS / 4)          /* 2,512,896 */
#define NQ_STATIC (N_WINDOWS * N_SERIES)  /* 418,816 */
#define NQ_COPY (NQ_OUTS + NQ_STATIC)
#define NQ_INS2 (N_WINDOWS * N_SERIES * 42) /* 17,590,272 */

#define SCAN_BLOCKS 16
#define COPY_BLOCKS 2048

typedef float f4 __attribute__((ext_vector_type(4)));

// ---------------------------------------------------------------------------
// Kernel 1 (fused):
//   blocks [0,16): exponential-smoothing scan. y is loaded DIRECTLY into
//     registers, 6 aligned float4 per 24-step chunk (24c floats = 96c bytes,
//     16B-aligned; row stride 2400B preserves alignment), double-buffered so
//     chunk c+1's loads are in flight during chunk c's compute. LDS is used
//     only on the STORE side: per-lane results -> barrier -> cooperative
//     coalesced global stores. Seasonal ring buffer sb[t%24] in registers
//     (chunks aligned so t%24 == step index j, all compile-time).
//   blocks [16,...): outsample copy + static s_matrix columns (independent
//     of the scan), nontemporal stores.
// ---------------------------------------------------------------------------
__global__ __launch_bounds__(64) void scan_copy_kernel(
    const float* __restrict__ y, const float* __restrict__ s_matrix,
    const float* __restrict__ embeds, const int* __restrict__ idxs,
    float* __restrict__ levels, float* __restrict__ seas1,
    f4* __restrict__ out_ins, f4* __restrict__ out_outs)
{
    __shared__ float buf_l[64][25];
    __shared__ float buf_s[64][25];

    if (blockIdx.x < SCAN_BLOCKS) {
        const int lane = threadIdx.x;
        const int s0 = blockIdx.x * 64;
        const int s = s0 + lane;
        const int row = idxs[s];
        const float* e = embeds + row * (2 + SEAS);

        const float lev_sms = 1.0f / (1.0f + __expf(-e[0]));
        const float seas_sms = 1.0f / (1.0f + __expf(-e[1]));
        const float one_m_lev = 1.0f - lev_sms;
        const float one_m_seas = 1.0f - seas_sms;

        const float* yrow = y + s * N_TIME;
        const f4* yv4 = (const f4*)yrow; // row offset 2400B -> 16B aligned

        f4 cur[6], nxt[6];
#pragma unroll
        for (int i = 0; i < 6; ++i) cur[i] = yv4[i]; // chunk 0: y[0..23]

        float sb[SEAS];
#pragma unroll
        for (int j = 0; j < SEAS; ++j) {
            float v = __expf(e[2 + j]);
            sb[j] = v;
            buf_s[lane][j] = v;
        }
        __syncthreads();
        // init seasonality cols 0..23, coalesced
#pragma unroll
        for (int k = 0; k < 24; ++k) {
            int i = lane + k * 64;
            int r = i / 24;
            int col = i - r * 24;
            seas1[(s0 + r) * SEAS_LEN + col] = buf_s[r][col];
        }
        seas1[s * SEAS_LEN + SEAS] = sb[0]; // col 24 = rolled init_seas[0]
        float lev = __fdividef(cur[0].x, sb[0]);
        levels[s * N_TIME] = lev;
        __syncthreads(); // buf_s reused below

        // ---- chunk 0: t = 1..23 (ring index = t) ----
        {
#pragma unroll
            for (int i = 0; i < 6; ++i) nxt[i] = yv4[6 + i]; // prefetch c=1
#pragma unroll
            for (int j = 0; j < 23; ++j) {
                const int t = j + 1;
                float yt = cur[t >> 2][t & 3];
                float st = sb[t];
                float newlev = lev_sms * __fdividef(yt, st) + one_m_lev * lev;
                float news =
                    seas_sms * __fdividef(yt, newlev) + one_m_seas * st;
                lev = newlev;
                sb[t] = news;
                buf_l[lane][j] = newlev;
                buf_s[lane][j] = news;
            }
            __syncthreads();
#pragma unroll
            for (int k = 0; k < 24; ++k) {
                int i = lane + k * 64;
                int r = i / 24;
                int col = i - r * 24;
                if (col < 23) {
                    levels[(s0 + r) * N_TIME + 1 + col] = buf_l[r][col];
                    seas1[(s0 + r) * SEAS_LEN + 25 + col] = buf_s[r][col];
                }
            }
            __syncthreads();
#pragma unroll
            for (int i = 0; i < 6; ++i) cur[i] = nxt[i];
        }

        // ---- chunks c = 1..24: t = 24c + j, j = 0..23, ring index = j ----
#pragma unroll 1
        for (int c = 1; c < 25; ++c) {
            const int t0 = 24 * c;
            if (c < 24) {
                const f4* p = (const f4*)(yrow + 24 * (c + 1));
#pragma unroll
                for (int i = 0; i < 6; ++i) nxt[i] = p[i];
            }
#pragma unroll
            for (int j = 0; j < 24; ++j) {
                float yt = cur[j >> 2][j & 3];
                float st = sb[j];
                float newlev = lev_sms * __fdividef(yt, st) + one_m_lev * lev;
                float news =
                    seas_sms * __fdividef(yt, newlev) + one_m_seas * st;
                lev = newlev;
                sb[j] = news;
                buf_l[lane][j] = newlev;
                buf_s[lane][j] = news;
            }
            __syncthreads();
#pragma unroll
            for (int k = 0; k < 24; ++k) {
                int i = lane + k * 64;
                int r = i / 24;
                int col = i - r * 24;
                levels[(s0 + r) * N_TIME + t0 + col] = buf_l[r][col];
                seas1[(s0 + r) * SEAS_LEN + SEAS + t0 + col] = buf_s[r][col];
            }
            __syncthreads();
#pragma unroll
            for (int i = 0; i < 6; ++i) cur[i] = nxt[i];
        }
    } else {
        // copy role: outsample windows + static s_matrix columns
        const f4* sm4 = (const f4*)s_matrix;
        int idx = (blockIdx.x - SCAN_BLOCKS) * 64 + threadIdx.x;
        const int stride = (gridDim.x - SCAN_BLOCKS) * 64;
        for (; idx < NQ_COPY; idx += stride) {
            if (idx < NQ_OUTS) {
                int rowq = idx / 6;
                int j4 = idx - rowq * 6;
                int w = rowq >> 10;
                int s = rowq & 1023;
                const float* yp = y + s * N_TIME + w + INPUT_SIZE + j4 * 4;
                f4 v = {yp[0], yp[1], yp[2], yp[3]};
                __builtin_nontemporal_store(v, &out_outs[idx]);
            } else {
                int j = idx - NQ_OUTS; // w*1024 + s
                int s = j & 1023;
                f4 v = sm4[s];
                __builtin_nontemporal_store(v, &out_ins[j * 43 + 42]);
            }
        }
    }
}

// ---------------------------------------------------------------------------
// Kernel 2: insample log-normalized windows (the 275 MB write stream).
// ---------------------------------------------------------------------------
__global__ __launch_bounds__(256) void ins_kernel(
    const float* __restrict__ y, const float* __restrict__ levels,
    const float* __restrict__ seas1, f4* __restrict__ out_ins)
{
    const int stride = gridDim.x * blockDim.x;
    for (int q = blockIdx.x * blockDim.x + threadIdx.x; q < NQ_INS2;
         q += stride) {
        int rowq = q / 42;
        int e4 = q - rowq * 42;
        int w = rowq >> 10;
        int s = rowq & 1023;
        int t = w + e4 * 4;
        float lev = levels[s * N_TIME + w + INPUT_SIZE - 1];
        const float* yp = y + s * N_TIME + t;
        const float* sp = seas1 + s * SEAS_LEN + t;
        float vv[4];
#pragma unroll
        for (int j = 0; j < 4; ++j)
            vv[j] = __logf(__fdividef(yp[j], lev * sp[j]));
        f4 v = {vv[0], vv[1], vv[2], vv[3]};
        __builtin_nontemporal_store(v, &out_ins[rowq * 43 + e4]);
    }
}

extern "C" void kernel_launch(void* const* d_in, const int* in_sizes, int n_in,
                              void* d_out, int out_size, void* d_ws, size_t ws_size,
                              hipStream_t stream) {
    const float* y      = (const float*)d_in[0];
    const float* sm     = (const float*)d_in[1];
    const float* embeds = (const float*)d_in[2];
    const int*   idxs   = (const int*)d_in[3];

    float* out      = (float*)d_out;
    float* out_ins  = out;
    float* out_outs = out + INS_ELEMS;
    float* out_lev  = out + INS_ELEMS + OUTS_ELEMS;
    float* out_seas = out_lev + LEV_ELEMS;

    scan_copy_kernel<<<SCAN_BLOCKS + COPY_BLOCKS, 64, 0, stream>>>(
        y, sm, embeds, idxs, out_lev, out_seas, (f4*)out_ins,
        (f4*)out_outs);
    ins_kernel<<<2048, 256, 0, stream>>>(y, out_lev, out_seas,
                                         (f4*)out_ins);
}

// Round 5
// 163.633 us; speedup vs baseline: 1.6427x; 1.1082x over previous
//
#include <hip/hip_runtime.h>

#define N_SERIES 1024
#define N_TIME 600
#define INPUT_SIZE 168
#define OUTPUT_SIZE 24
#define N_S 4
#define SEAS 24
#define N_WINDOWS (N_TIME - INPUT_SIZE - OUTPUT_SIZE + 1) /* 409 */
#define SEAS_LEN (N_TIME + SEAS)                          /* 624 */

#define INS_ELEMS (N_WINDOWS * N_SERIES * (INPUT_SIZE + N_S)) /* 72,036,352 */
#define OUTS_ELEMS (N_WINDOWS * N_SERIES * OUTPUT_SIZE)       /* 10,051,584 */
#define LEV_ELEMS (N_SERIES * N_TIME)
#define SEAS_ELEMS (N_SERIES * SEAS_LEN)

#define NQ_OUTS (OUTS_ELEMS / 4)              /* 2,512,896 */
#define NQ_INS43 (N_WINDOWS * N_SERIES * 43)  /* 18,009,088 */

#define SCAN_BLOCKS 16
#define COPY_BLOCKS 2048
#define WS_NEEDED (2u * LEV_ELEMS * sizeof(float)) /* tbl + loglev = 4.9 MB */

typedef float f4 __attribute__((ext_vector_type(4)));

// ---------------------------------------------------------------------------
// Kernel 1 (fused):
//   blocks [0,16): exponential-smoothing scan. y loaded straight into
//     registers (6 aligned float4 / 24-step chunk, double-buffered). Results
//     staged per-chunk in LDS, then cooperatively stored COALESCED (per-lane
//     scatter costs ~64 TA-cycles/instr — avoid). Also emits two ws tables:
//       tbl[s][t]    = log(y_t / s_t)      (= log(q1), q1 already computed)
//       loglev[s][t] = log(levels[s][t])
//   blocks [16,...): outsample window copy (dense contiguous writes).
// ---------------------------------------------------------------------------
__global__ __launch_bounds__(64) void scan_copy_kernel(
    const float* __restrict__ y, const float* __restrict__ embeds,
    const int* __restrict__ idxs, float* __restrict__ levels,
    float* __restrict__ seas1, float* __restrict__ tbl,
    float* __restrict__ loglev, f4* __restrict__ out_outs, int have_ws)
{
    __shared__ float b_lev[64][25];
    __shared__ float b_sea[64][25];
    __shared__ float b_tbl[64][25];
    __shared__ float b_llv[64][25];

    if (blockIdx.x < SCAN_BLOCKS) {
        const int lane = threadIdx.x;
        const int s0 = blockIdx.x * 64;
        const int s = s0 + lane;
        const int row = idxs[s];
        const float* e = embeds + row * (2 + SEAS);

        const float lev_sms = 1.0f / (1.0f + __expf(-e[0]));
        const float seas_sms = 1.0f / (1.0f + __expf(-e[1]));
        const float one_m_lev = 1.0f - lev_sms;
        const float one_m_seas = 1.0f - seas_sms;

        const float* yrow = y + s * N_TIME;
        const f4* yv4 = (const f4*)yrow; // row stride 2400B keeps 16B align

        f4 cur[6], nxt[6];
#pragma unroll
        for (int i = 0; i < 6; ++i) cur[i] = yv4[i];

        float sb[SEAS];
#pragma unroll
        for (int j = 0; j < SEAS; ++j) {
            float v = __expf(e[2 + j]);
            sb[j] = v;
            b_sea[lane][j] = v;
        }
        __syncthreads();
        // init seasonality cols 0..23, coalesced
#pragma unroll
        for (int k = 0; k < 24; ++k) {
            int i = lane + k * 64;
            int r = i / 24;
            int col = i - r * 24;
            seas1[(s0 + r) * SEAS_LEN + col] = b_sea[r][col];
        }
        seas1[s * SEAS_LEN + SEAS] = sb[0]; // col 24 = rolled init_seas[0]
        float lev = __fdividef(cur[0].x, sb[0]);
        levels[s * N_TIME] = lev;
        if (have_ws) {
            float l0 = __logf(lev);
            tbl[s * N_TIME] = l0;    // log(y0/s0)
            loglev[s * N_TIME] = l0; // log(level0) — same value
        }
        __syncthreads(); // b_sea reused below

        // ---- chunk 0: t = 1..23 (ring index = t) ----
        {
#pragma unroll
            for (int i = 0; i < 6; ++i) nxt[i] = yv4[6 + i];
#pragma unroll
            for (int j = 0; j < 23; ++j) {
                const int t = j + 1;
                float yt = cur[t >> 2][t & 3];
                float st = sb[t];
                float q1 = __fdividef(yt, st);
                float newlev = lev_sms * q1 + one_m_lev * lev;
                float news =
                    seas_sms * __fdividef(yt, newlev) + one_m_seas * st;
                lev = newlev;
                sb[t] = news;
                b_lev[lane][j] = newlev;
                b_sea[lane][j] = news;
                b_tbl[lane][j] = __logf(q1);
                b_llv[lane][j] = __logf(newlev);
            }
            __syncthreads();
#pragma unroll
            for (int k = 0; k < 24; ++k) {
                int i = lane + k * 64;
                int r = i / 24;
                int col = i - r * 24;
                if (col < 23) {
                    int sr = s0 + r;
                    levels[sr * N_TIME + 1 + col] = b_lev[r][col];
                    seas1[sr * SEAS_LEN + 25 + col] = b_sea[r][col];
                    if (have_ws) {
                        tbl[sr * N_TIME + 1 + col] = b_tbl[r][col];
                        loglev[sr * N_TIME + 1 + col] = b_llv[r][col];
                    }
                }
            }
            __syncthreads();
#pragma unroll
            for (int i = 0; i < 6; ++i) cur[i] = nxt[i];
        }

        // ---- chunks c = 1..24: t = 24c + j, ring index = j ----
#pragma unroll 1
        for (int c = 1; c < 25; ++c) {
            const int t0 = 24 * c;
            if (c < 24) {
                const f4* p = (const f4*)(yrow + 24 * (c + 1));
#pragma unroll
                for (int i = 0; i < 6; ++i) nxt[i] = p[i];
            }
#pragma unroll
            for (int j = 0; j < 24; ++j) {
                float yt = cur[j >> 2][j & 3];
                float st = sb[j];
                float q1 = __fdividef(yt, st);
                float newlev = lev_sms * q1 + one_m_lev * lev;
                float news =
                    seas_sms * __fdividef(yt, newlev) + one_m_seas * st;
                lev = newlev;
                sb[j] = news;
                b_lev[lane][j] = newlev;
                b_sea[lane][j] = news;
                b_tbl[lane][j] = __logf(q1);
                b_llv[lane][j] = __logf(newlev);
            }
            __syncthreads();
#pragma unroll
            for (int k = 0; k < 24; ++k) {
                int i = lane + k * 64;
                int r = i / 24;
                int col = i - r * 24;
                int sr = s0 + r;
                levels[sr * N_TIME + t0 + col] = b_lev[r][col];
                seas1[sr * SEAS_LEN + SEAS + t0 + col] = b_sea[r][col];
                if (have_ws) {
                    tbl[sr * N_TIME + t0 + col] = b_tbl[r][col];
                    loglev[sr * N_TIME + t0 + col] = b_llv[r][col];
                }
            }
            __syncthreads();
#pragma unroll
            for (int i = 0; i < 6; ++i) cur[i] = nxt[i];
        }
    } else {
        // copy role: outsample windows (dense contiguous 40 MB)
        int idx = (blockIdx.x - SCAN_BLOCKS) * 64 + threadIdx.x;
        const int stride = (gridDim.x - SCAN_BLOCKS) * 64;
        for (; idx < NQ_OUTS; idx += stride) {
            int rowq = idx / 6;
            int j4 = idx - rowq * 6;
            int w = rowq >> 10;
            int s = rowq & 1023;
            const float* yp = y + s * N_TIME + w + INPUT_SIZE + j4 * 4;
            f4 v = {yp[0], yp[1], yp[2], yp[3]};
            out_outs[idx] = v;
        }
    }
}

// ---------------------------------------------------------------------------
// Kernel 2 (fast path): insample rows incl. static column — fully dense
// 288 MB write stream. Per float4: 5 dword loads + 4 subs (log-difference).
// ---------------------------------------------------------------------------
__global__ __launch_bounds__(256) void ins_kernel(
    const float* __restrict__ tbl, const float* __restrict__ loglev,
    const float* __restrict__ s_matrix, f4* __restrict__ out_ins)
{
    const f4* sm4 = (const f4*)s_matrix;
    const int stride = gridDim.x * blockDim.x;
    for (int q = blockIdx.x * blockDim.x + threadIdx.x; q < NQ_INS43;
         q += stride) {
        int rowq = q / 43;
        int e4 = q - rowq * 43;
        int w = rowq >> 10;
        int s = rowq & 1023;
        f4 v;
        if (e4 == 42) {
            v = sm4[s];
        } else {
            int t = w + e4 * 4;
            const float* tp = tbl + s * N_TIME + t;
            float llv = loglev[s * N_TIME + w + INPUT_SIZE - 1];
            v.x = tp[0] - llv;
            v.y = tp[1] - llv;
            v.z = tp[2] - llv;
            v.w = tp[3] - llv;
        }
        out_ins[q] = v;
    }
}

// Fallback (ws too small): compute logs on the fly.
__global__ __launch_bounds__(256) void ins_kernel_fb(
    const float* __restrict__ y, const float* __restrict__ levels,
    const float* __restrict__ seas1, const float* __restrict__ s_matrix,
    f4* __restrict__ out_ins)
{
    const f4* sm4 = (const f4*)s_matrix;
    const int stride = gridDim.x * blockDim.x;
    for (int q = blockIdx.x * blockDim.x + threadIdx.x; q < NQ_INS43;
         q += stride) {
        int rowq = q / 43;
        int e4 = q - rowq * 43;
        int w = rowq >> 10;
        int s = rowq & 1023;
        f4 v;
        if (e4 == 42) {
            v = sm4[s];
        } else {
            int t = w + e4 * 4;
            float lev = levels[s * N_TIME + w + INPUT_SIZE - 1];
            const float* yp = y + s * N_TIME + t;
            const float* sp = seas1 + s * SEAS_LEN + t;
            float vv[4];
#pragma unroll
            for (int j = 0; j < 4; ++j)
                vv[j] = __logf(__fdividef(yp[j], lev * sp[j]));
            v.x = vv[0]; v.y = vv[1]; v.z = vv[2]; v.w = vv[3];
        }
        out_ins[q] = v;
    }
}

extern "C" void kernel_launch(void* const* d_in, const int* in_sizes, int n_in,
                              void* d_out, int out_size, void* d_ws, size_t ws_size,
                              hipStream_t stream) {
    const float* y      = (const float*)d_in[0];
    const float* sm     = (const float*)d_in[1];
    const float* embeds = (const float*)d_in[2];
    const int*   idxs   = (const int*)d_in[3];

    float* out      = (float*)d_out;
    float* out_ins  = out;
    float* out_outs = out + INS_ELEMS;
    float* out_lev  = out + INS_ELEMS + OUTS_ELEMS;
    float* out_seas = out_lev + LEV_ELEMS;

    float* tbl    = (float*)d_ws;
    float* loglev = tbl + LEV_ELEMS;
    const int have_ws = (ws_size >= (size_t)WS_NEEDED) ? 1 : 0;

    scan_copy_kernel<<<SCAN_BLOCKS + COPY_BLOCKS, 64, 0, stream>>>(
        y, embeds, idxs, out_lev, out_seas, tbl, loglev, (f4*)out_outs,
        have_ws);
    if (have_ws) {
        ins_kernel<<<2048, 256, 0, stream>>>(tbl, loglev, sm, (f4*)out_ins);
    } else {
        ins_kernel_fb<<<2048, 256, 0, stream>>>(y, out_lev, out_seas, sm,
                                                (f4*)out_ins);
    }
}

// Round 6
// 142.988 us; speedup vs baseline: 1.8798x; 1.1444x over previous
//
#include <hip/hip_runtime.h>

#define N_SERIES 1024
#define N_TIME 600
#define INPUT_SIZE 168
#define OUTPUT_SIZE 24
#define N_S 4
#define SEAS 24
#define N_WINDOWS (N_TIME - INPUT_SIZE - OUTPUT_SIZE + 1) /* 409 */
#define SEAS_LEN (N_TIME + SEAS)                          /* 624 */

#define INS_ELEMS (N_WINDOWS * N_SERIES * (INPUT_SIZE + N_S)) /* 72,036,352 */
#define OUTS_ELEMS (N_WINDOWS * N_SERIES * OUTPUT_SIZE)       /* 10,051,584 */
#define LEV_ELEMS (N_SERIES * N_TIME)
#define SEAS_ELEMS (N_SERIES * SEAS_LEN)

#define NQ_OUTS (OUTS_ELEMS / 4)              /* 2,512,896 */
#define NQ_INS43 (N_WINDOWS * N_SERIES * 43)  /* 18,009,088 */

#define SCAN_BLOCKS 8   /* 128 threads each -> 1024 series */
#define COPY_BLOCKS 2048
#define SCAN_T 128
#define WS_NEEDED (2u * LEV_ELEMS * sizeof(float)) /* tbl + loglev = 4.9 MB */

typedef float f4 __attribute__((ext_vector_type(4)));

// lgkm-only barrier: global-store acks do NOT need draining inside the scan
// loop (tables are only read by the NEXT kernel); skipping the compiler's
// vmcnt(0)-before-s_barrier removes ~700 exposed cycles per barrier.
#define BARRIER_LGKM() asm volatile("s_waitcnt lgkmcnt(0)\n\ts_barrier" ::: "memory")

// ---------------------------------------------------------------------------
// Kernel 1 (fused):
//   blocks [0,8): exponential-smoothing scan, 128 threads (2 waves) so one
//     wave's stalls hide under the other's compute. y loaded to registers
//     (6 aligned float4/chunk, double-buffered). Per chunk: compute 24 steps
//     into LDS -> lgkm barrier -> cooperative float4 global stores (16B-
//     aligned, t0 = 24c) -> lgkm barrier. Ring buffer sb[t%24] in registers,
//     all indices compile-time.
//   blocks [8,...): outsample window copy (independent of scan).
// ---------------------------------------------------------------------------
__global__ __launch_bounds__(SCAN_T) void scan_copy_kernel(
    const float* __restrict__ y, const float* __restrict__ embeds,
    const int* __restrict__ idxs, float* __restrict__ levels,
    float* __restrict__ seas1, float* __restrict__ tbl,
    float* __restrict__ loglev, f4* __restrict__ out_outs, int have_ws)
{
    // [SCAN_T][25]: 100B rows -> ds_write bank (25*tid+j)%32, 2-way max (free)
    __shared__ float b_lev[SCAN_T][25];
    __shared__ float b_sea[SCAN_T][25];
    __shared__ float b_tbl[SCAN_T][25];
    __shared__ float b_llv[SCAN_T][25];

    if (blockIdx.x < SCAN_BLOCKS) {
        const int tid = threadIdx.x;
        const int s0 = blockIdx.x * SCAN_T;
        const int s = s0 + tid;
        const int row = idxs[s];
        const float* e = embeds + row * (2 + SEAS);

        const float lev_sms = 1.0f / (1.0f + __expf(-e[0]));
        const float seas_sms = 1.0f / (1.0f + __expf(-e[1]));
        const float one_m_lev = 1.0f - lev_sms;
        const float one_m_seas = 1.0f - seas_sms;

        const float* yrow = y + s * N_TIME;
        const f4* yv4 = (const f4*)yrow; // row stride 2400B keeps 16B align

        f4 cur[6], nxt[6];
#pragma unroll
        for (int i = 0; i < 6; ++i) cur[i] = yv4[i];

        float sb[SEAS];
#pragma unroll
        for (int j = 0; j < SEAS; ++j) {
            float v = __expf(e[2 + j]);
            sb[j] = v;
            b_sea[tid][j] = v;
        }
        BARRIER_LGKM();
        // init seasonality cols 0..23: cooperative float4 stores (aligned)
#pragma unroll
        for (int k4 = 0; k4 < 6; ++k4) {
            int q4 = tid + k4 * SCAN_T;
            int r = q4 / 6;
            int c4 = q4 - r * 6;
            f4 v = {b_sea[r][c4 * 4 + 0], b_sea[r][c4 * 4 + 1],
                    b_sea[r][c4 * 4 + 2], b_sea[r][c4 * 4 + 3]};
            *(f4*)(seas1 + (s0 + r) * SEAS_LEN + c4 * 4) = v;
        }
        seas1[s * SEAS_LEN + SEAS] = sb[0]; // col 24 = rolled init_seas[0]
        float lev = __fdividef(cur[0].x, sb[0]);
        levels[s * N_TIME] = lev;
        if (have_ws) {
            float l0 = __logf(lev);
            tbl[s * N_TIME] = l0;
            loglev[s * N_TIME] = l0;
        }
        BARRIER_LGKM(); // b_sea reused below

        // ---- chunk 0: t = 1..23 (ring index = t), scalar store path ----
        {
#pragma unroll
            for (int i = 0; i < 6; ++i) nxt[i] = yv4[6 + i];
#pragma unroll
            for (int j = 0; j < 23; ++j) {
                const int t = j + 1;
                float yt = cur[t >> 2][t & 3];
                float st = sb[t];
                float q1 = __fdividef(yt, st);
                float newlev = lev_sms * q1 + one_m_lev * lev;
                float news =
                    seas_sms * __fdividef(yt, newlev) + one_m_seas * st;
                lev = newlev;
                sb[t] = news;
                b_lev[tid][j] = newlev;
                b_sea[tid][j] = news;
                b_tbl[tid][j] = __logf(q1);
                b_llv[tid][j] = __logf(newlev);
            }
            BARRIER_LGKM();
#pragma unroll
            for (int k = 0; k < 24; ++k) {
                int i = tid + k * SCAN_T;
                int r = i / 24;
                int col = i - r * 24;
                if (col < 23) {
                    int sr = s0 + r;
                    levels[sr * N_TIME + 1 + col] = b_lev[r][col];
                    seas1[sr * SEAS_LEN + 25 + col] = b_sea[r][col];
                    if (have_ws) {
                        tbl[sr * N_TIME + 1 + col] = b_tbl[r][col];
                        loglev[sr * N_TIME + 1 + col] = b_llv[r][col];
                    }
                }
            }
            BARRIER_LGKM();
#pragma unroll
            for (int i = 0; i < 6; ++i) cur[i] = nxt[i];
        }

        // ---- chunks c = 1..24: t = 24c + j, ring index = j ----
#pragma unroll 1
        for (int c = 1; c < 25; ++c) {
            const int t0 = 24 * c;
            if (c < 24) {
                const f4* p = (const f4*)(yrow + 24 * (c + 1));
#pragma unroll
                for (int i = 0; i < 6; ++i) nxt[i] = p[i];
            }
#pragma unroll
            for (int j = 0; j < 24; ++j) {
                float yt = cur[j >> 2][j & 3];
                float st = sb[j];
                float q1 = __fdividef(yt, st);
                float newlev = lev_sms * q1 + one_m_lev * lev;
                float news =
                    seas_sms * __fdividef(yt, newlev) + one_m_seas * st;
                lev = newlev;
                sb[j] = news;
                b_lev[tid][j] = newlev;
                b_sea[tid][j] = news;
                b_tbl[tid][j] = __logf(q1);
                b_llv[tid][j] = __logf(newlev);
            }
            BARRIER_LGKM();
            // cooperative float4 stores: t0 = 24c -> 96c bytes, 16B-aligned
#pragma unroll
            for (int k4 = 0; k4 < 6; ++k4) {
                int q4 = tid + k4 * SCAN_T;
                int r = q4 / 6;
                int c4 = q4 - r * 6;
                int sr = s0 + r;
                int cc = c4 * 4;
                f4 vl = {b_lev[r][cc], b_lev[r][cc + 1], b_lev[r][cc + 2],
                         b_lev[r][cc + 3]};
                *(f4*)(levels + sr * N_TIME + t0 + cc) = vl;
                f4 vs = {b_sea[r][cc], b_sea[r][cc + 1], b_sea[r][cc + 2],
                         b_sea[r][cc + 3]};
                *(f4*)(seas1 + sr * SEAS_LEN + SEAS + t0 + cc) = vs;
                if (have_ws) {
                    f4 vt = {b_tbl[r][cc], b_tbl[r][cc + 1], b_tbl[r][cc + 2],
                             b_tbl[r][cc + 3]};
                    *(f4*)(tbl + sr * N_TIME + t0 + cc) = vt;
                    f4 vv = {b_llv[r][cc], b_llv[r][cc + 1], b_llv[r][cc + 2],
                             b_llv[r][cc + 3]};
                    *(f4*)(loglev + sr * N_TIME + t0 + cc) = vv;
                }
            }
            BARRIER_LGKM();
#pragma unroll
            for (int i = 0; i < 6; ++i) cur[i] = nxt[i];
        }
    } else {
        // copy role: outsample windows (dense contiguous 40 MB)
        int idx = (blockIdx.x - SCAN_BLOCKS) * SCAN_T + threadIdx.x;
        const int stride = (gridDim.x - SCAN_BLOCKS) * SCAN_T;
        for (; idx < NQ_OUTS; idx += stride) {
            int rowq = idx / 6;
            int j4 = idx - rowq * 6;
            int w = rowq >> 10;
            int s = rowq & 1023;
            const float* yp = y + s * N_TIME + w + INPUT_SIZE + j4 * 4;
            f4 v = {yp[0], yp[1], yp[2], yp[3]};
            out_outs[idx] = v;
        }
    }
}

// ---------------------------------------------------------------------------
// Kernel 2 (fast path): insample rows incl. static column — fully dense
// 288 MB write stream. Per float4: 5 dword loads + 4 subs (log-difference).
// ---------------------------------------------------------------------------
__global__ __launch_bounds__(256) void ins_kernel(
    const float* __restrict__ tbl, const float* __restrict__ loglev,
    const float* __restrict__ s_matrix, f4* __restrict__ out_ins)
{
    const f4* sm4 = (const f4*)s_matrix;
    const int stride = gridDim.x * blockDim.x;
    for (int q = blockIdx.x * blockDim.x + threadIdx.x; q < NQ_INS43;
         q += stride) {
        int rowq = q / 43;
        int e4 = q - rowq * 43;
        int w = rowq >> 10;
        int s = rowq & 1023;
        f4 v;
        if (e4 == 42) {
            v = sm4[s];
        } else {
            int t = w + e4 * 4;
            const float* tp = tbl + s * N_TIME + t;
            float llv = loglev[s * N_TIME + w + INPUT_SIZE - 1];
            v.x = tp[0] - llv;
            v.y = tp[1] - llv;
            v.z = tp[2] - llv;
            v.w = tp[3] - llv;
        }
        out_ins[q] = v;
    }
}

// Fallback (ws too small): compute logs on the fly.
__global__ __launch_bounds__(256) void ins_kernel_fb(
    const float* __restrict__ y, const float* __restrict__ levels,
    const float* __restrict__ seas1, const float* __restrict__ s_matrix,
    f4* __restrict__ out_ins)
{
    const f4* sm4 = (const f4*)s_matrix;
    const int stride = gridDim.x * blockDim.x;
    for (int q = blockIdx.x * blockDim.x + threadIdx.x; q < NQ_INS43;
         q += stride) {
        int rowq = q / 43;
        int e4 = q - rowq * 43;
        int w = rowq >> 10;
        int s = rowq & 1023;
        f4 v;
        if (e4 == 42) {
            v = sm4[s];
        } else {
            int t = w + e4 * 4;
            float lev = levels[s * N_TIME + w + INPUT_SIZE - 1];
            const float* yp = y + s * N_TIME + t;
            const float* sp = seas1 + s * SEAS_LEN + t;
            float vv[4];
#pragma unroll
            for (int j = 0; j < 4; ++j)
                vv[j] = __logf(__fdividef(yp[j], lev * sp[j]));
            v.x = vv[0]; v.y = vv[1]; v.z = vv[2]; v.w = vv[3];
        }
        out_ins[q] = v;
    }
}

extern "C" void kernel_launch(void* const* d_in, const int* in_sizes, int n_in,
                              void* d_out, int out_size, void* d_ws, size_t ws_size,
                              hipStream_t stream) {
    const float* y      = (const float*)d_in[0];
    const float* sm     = (const float*)d_in[1];
    const float* embeds = (const float*)d_in[2];
    const int*   idxs   = (const int*)d_in[3];

    float* out      = (float*)d_out;
    float* out_ins  = out;
    float* out_outs = out + INS_ELEMS;
    float* out_lev  = out + INS_ELEMS + OUTS_ELEMS;
    float* out_seas = out_lev + LEV_ELEMS;

    float* tbl    = (float*)d_ws;
    float* loglev = tbl + LEV_ELEMS;
    const int have_ws = (ws_size >= (size_t)WS_NEEDED) ? 1 : 0;

    scan_copy_kernel<<<SCAN_BLOCKS + COPY_BLOCKS, SCAN_T, 0, stream>>>(
        y, embeds, idxs, out_lev, out_seas, tbl, loglev, (f4*)out_outs,
        have_ws);
    if (have_ws) {
        ins_kernel<<<2048, 256, 0, stream>>>(tbl, loglev, sm, (f4*)out_ins);
    } else {
        ins_kernel_fb<<<2048, 256, 0, stream>>>(y, out_lev, out_seas, sm,
                                                (f4*)out_ins);
    }
}

// Round 7
// 121.639 us; speedup vs baseline: 2.2098x; 1.1755x over previous
//
#include <hip/hip_runtime.h>

#define N_SERIES 1024
#define N_TIME 600
#define INPUT_SIZE 168
#define OUTPUT_SIZE 24
#define N_S 4
#define SEAS 24
#define N_WINDOWS (N_TIME - INPUT_SIZE - OUTPUT_SIZE + 1) /* 409 */
#define SEAS_LEN (N_TIME + SEAS)                          /* 624 */

#define INS_ELEMS (N_WINDOWS * N_SERIES * (INPUT_SIZE + N_S)) /* 72,036,352 */
#define OUTS_ELEMS (N_WINDOWS * N_SERIES * OUTPUT_SIZE)       /* 10,051,584 */
#define LEV_ELEMS (N_SERIES * N_TIME)
#define SEAS_ELEMS (N_SERIES * SEAS_LEN)

#define NQ_OUTS (OUTS_ELEMS / 4)              /* 2,512,896 */
#define NQ_INS43 (N_WINDOWS * N_SERIES * 43)  /* 18,009,088 */
#define INS_SLICE (NQ_INS43 / 8)              /* 2,251,136 (row-aligned: 43|SLICE) */

#define SCAN_BLOCKS 8
#define COPY_BLOCKS 2048
#define SCAN_T 128
#define WS_NEEDED (3u * LEV_ELEMS * sizeof(float)) /* q1raw + tbl + llv */

typedef float f4 __attribute__((ext_vector_type(4)));

// lgkm-only barrier: global-store acks don't need draining inside the scan
// loop (tables are read only by LATER kernels); skips the compiler's
// vmcnt(0)-before-s_barrier drain.
#define BARRIER_LGKM() asm volatile("s_waitcnt lgkmcnt(0)\n\ts_barrier" ::: "memory")

// ---------------------------------------------------------------------------
// Kernel 1 (fused):
//   blocks [0,8): exponential-smoothing scan, 128 threads. NO transcendentals
//     in the loop except 2 rcp: logs are deferred to logpass_kernel. Emits
//     levels, seas1 (outputs) and q1raw[s][t] = y_t/s_t (ws).
//   blocks [8,...): outsample window copy.
// ---------------------------------------------------------------------------
__global__ __launch_bounds__(SCAN_T) void scan_copy_kernel(
    const float* __restrict__ y, const float* __restrict__ embeds,
    const int* __restrict__ idxs, float* __restrict__ levels,
    float* __restrict__ seas1, float* __restrict__ q1raw,
    f4* __restrict__ out_outs, int have_ws)
{
    __shared__ float b_lev[SCAN_T][25];
    __shared__ float b_sea[SCAN_T][25];
    __shared__ float b_q1[SCAN_T][25];

    if (blockIdx.x < SCAN_BLOCKS) {
        const int tid = threadIdx.x;
        const int s0 = blockIdx.x * SCAN_T;
        const int s = s0 + tid;
        const int row = idxs[s];
        const float* e = embeds + row * (2 + SEAS);

        const float lev_sms = 1.0f / (1.0f + __expf(-e[0]));
        const float seas_sms = 1.0f / (1.0f + __expf(-e[1]));
        const float one_m_lev = 1.0f - lev_sms;
        const float one_m_seas = 1.0f - seas_sms;

        const float* yrow = y + s * N_TIME;
        const f4* yv4 = (const f4*)yrow; // row stride 2400B keeps 16B align

        f4 cur[6], nxt[6];
#pragma unroll
        for (int i = 0; i < 6; ++i) cur[i] = yv4[i];

        float sb[SEAS];
#pragma unroll
        for (int j = 0; j < SEAS; ++j) {
            float v = __expf(e[2 + j]);
            sb[j] = v;
            b_sea[tid][j] = v;
        }
        BARRIER_LGKM();
        // init seasonality cols 0..23: cooperative float4 stores (aligned)
#pragma unroll
        for (int k4 = 0; k4 < 6; ++k4) {
            int q4 = tid + k4 * SCAN_T;
            int r = q4 / 6;
            int c4 = q4 - r * 6;
            f4 v = {b_sea[r][c4 * 4 + 0], b_sea[r][c4 * 4 + 1],
                    b_sea[r][c4 * 4 + 2], b_sea[r][c4 * 4 + 3]};
            *(f4*)(seas1 + (s0 + r) * SEAS_LEN + c4 * 4) = v;
        }
        seas1[s * SEAS_LEN + SEAS] = sb[0]; // col 24 = rolled init_seas[0]
        float lev = __fdividef(cur[0].x, sb[0]);
        levels[s * N_TIME] = lev;
        if (have_ws) q1raw[s * N_TIME] = lev; // y0/s0 == level0
        BARRIER_LGKM(); // b_sea reused below

        // ---- chunk 0: t = 1..23 (ring index = t), scalar store path ----
        {
#pragma unroll
            for (int i = 0; i < 6; ++i) nxt[i] = yv4[6 + i];
#pragma unroll
            for (int j = 0; j < 23; ++j) {
                const int t = j + 1;
                float yt = cur[t >> 2][t & 3];
                float st = sb[t];
                float q1 = __fdividef(yt, st);
                float newlev = lev_sms * q1 + one_m_lev * lev;
                float news =
                    seas_sms * __fdividef(yt, newlev) + one_m_seas * st;
                lev = newlev;
                sb[t] = news;
                b_lev[tid][j] = newlev;
                b_sea[tid][j] = news;
                b_q1[tid][j] = q1;
            }
            BARRIER_LGKM();
#pragma unroll
            for (int k = 0; k < 24; ++k) {
                int i = tid + k * SCAN_T;
                int r = i / 24;
                int col = i - r * 24;
                if (col < 23) {
                    int sr = s0 + r;
                    levels[sr * N_TIME + 1 + col] = b_lev[r][col];
                    seas1[sr * SEAS_LEN + 25 + col] = b_sea[r][col];
                    if (have_ws) q1raw[sr * N_TIME + 1 + col] = b_q1[r][col];
                }
            }
            BARRIER_LGKM();
#pragma unroll
            for (int i = 0; i < 6; ++i) cur[i] = nxt[i];
        }

        // ---- chunks c = 1..24: t = 24c + j, ring index = j ----
#pragma unroll 1
        for (int c = 1; c < 25; ++c) {
            const int t0 = 24 * c;
            if (c < 24) {
                const f4* p = (const f4*)(yrow + 24 * (c + 1));
#pragma unroll
                for (int i = 0; i < 6; ++i) nxt[i] = p[i];
            }
#pragma unroll
            for (int j = 0; j < 24; ++j) {
                float yt = cur[j >> 2][j & 3];
                float st = sb[j];
                float q1 = __fdividef(yt, st);
                float newlev = lev_sms * q1 + one_m_lev * lev;
                float news =
                    seas_sms * __fdividef(yt, newlev) + one_m_seas * st;
                lev = newlev;
                sb[j] = news;
                b_lev[tid][j] = newlev;
                b_sea[tid][j] = news;
                b_q1[tid][j] = q1;
            }
            BARRIER_LGKM();
            // cooperative float4 stores: t0 = 24c -> 96c bytes, 16B-aligned
#pragma unroll
            for (int k4 = 0; k4 < 6; ++k4) {
                int q4 = tid + k4 * SCAN_T;
                int r = q4 / 6;
                int c4 = q4 - r * 6;
                int sr = s0 + r;
                int cc = c4 * 4;
                f4 vl = {b_lev[r][cc], b_lev[r][cc + 1], b_lev[r][cc + 2],
                         b_lev[r][cc + 3]};
                *(f4*)(levels + sr * N_TIME + t0 + cc) = vl;
                f4 vs = {b_sea[r][cc], b_sea[r][cc + 1], b_sea[r][cc + 2],
                         b_sea[r][cc + 3]};
                *(f4*)(seas1 + sr * SEAS_LEN + SEAS + t0 + cc) = vs;
                if (have_ws) {
                    f4 vq = {b_q1[r][cc], b_q1[r][cc + 1], b_q1[r][cc + 2],
                             b_q1[r][cc + 3]};
                    *(f4*)(q1raw + sr * N_TIME + t0 + cc) = vq;
                }
            }
            BARRIER_LGKM();
#pragma unroll
            for (int i = 0; i < 6; ++i) cur[i] = nxt[i];
        }
    } else {
        // copy role: outsample windows (dense contiguous 40 MB)
        int idx = (blockIdx.x - SCAN_BLOCKS) * SCAN_T + threadIdx.x;
        const int stride = (gridDim.x - SCAN_BLOCKS) * SCAN_T;
        for (; idx < NQ_OUTS; idx += stride) {
            int rowq = idx / 6;
            int j4 = idx - rowq * 6;
            int w = rowq >> 10;
            int s = rowq & 1023;
            const float* yp = y + s * N_TIME + w + INPUT_SIZE + j4 * 4;
            f4 v = {yp[0], yp[1], yp[2], yp[3]};
            out_outs[idx] = v;
        }
    }
}

// ---------------------------------------------------------------------------
// Kernel 2: full-GPU parallel log pass. tbl = log(q1raw), llv = log(levels).
// 153600 float4-threads, coalesced; ~3 us.
// ---------------------------------------------------------------------------
__global__ __launch_bounds__(256) void logpass_kernel(
    const float* __restrict__ q1raw, const float* __restrict__ levels,
    float* __restrict__ tbl, float* __restrict__ llv)
{
    int i = blockIdx.x * 256 + threadIdx.x; // one f4 per thread
    const f4* q4 = (const f4*)q1raw;
    const f4* l4 = (const f4*)levels;
    f4 a = q4[i], b = l4[i], ta, tb;
    ta.x = __logf(a.x); ta.y = __logf(a.y); ta.z = __logf(a.z); ta.w = __logf(a.w);
    tb.x = __logf(b.x); tb.y = __logf(b.y); tb.z = __logf(b.z); tb.w = __logf(b.w);
    ((f4*)tbl)[i] = ta;
    ((f4*)llv)[i] = tb;
}

// ---------------------------------------------------------------------------
// Kernel 3 (fast path): insample rows incl. static column — 288 MB dense
// write stream. XCD-clustered q mapping: block b -> xcd b&7 owns contiguous
// 1/8 q-slice, so each XCD's L2 working set is ~0.9 MB of tbl (pure hits)
// instead of thrashing 4 MB.
// ---------------------------------------------------------------------------
__global__ __launch_bounds__(256) void ins_kernel(
    const float* __restrict__ tbl, const float* __restrict__ llv,
    const float* __restrict__ s_matrix, f4* __restrict__ out_ins)
{
    const f4* sm4 = (const f4*)s_matrix;
    const int xcd = blockIdx.x & 7;
    const int lb = blockIdx.x >> 3; // 0..255
    const int qend = (xcd + 1) * INS_SLICE;
    const int stride = (COPY_BLOCKS / 8) * 256; /* 65536 */
    for (int q = xcd * INS_SLICE + lb * 256 + (int)threadIdx.x; q < qend;
         q += stride) {
        int rowq = q / 43;
        int e4 = q - rowq * 43;
        int w = rowq >> 10;
        int s = rowq & 1023;
        f4 v;
        if (e4 == 42) {
            v = sm4[s];
        } else {
            int t = w + e4 * 4;
            const float* tp = tbl + s * N_TIME + t;
            float lv = llv[s * N_TIME + w + INPUT_SIZE - 1];
            v.x = tp[0] - lv;
            v.y = tp[1] - lv;
            v.z = tp[2] - lv;
            v.w = tp[3] - lv;
        }
        out_ins[q] = v;
    }
}

// Fallback (ws too small): compute logs on the fly, same XCD clustering.
__global__ __launch_bounds__(256) void ins_kernel_fb(
    const float* __restrict__ y, const float* __restrict__ levels,
    const float* __restrict__ seas1, const float* __restrict__ s_matrix,
    f4* __restrict__ out_ins)
{
    const f4* sm4 = (const f4*)s_matrix;
    const int xcd = blockIdx.x & 7;
    const int lb = blockIdx.x >> 3;
    const int qend = (xcd + 1) * INS_SLICE;
    const int stride = (COPY_BLOCKS / 8) * 256;
    for (int q = xcd * INS_SLICE + lb * 256 + (int)threadIdx.x; q < qend;
         q += stride) {
        int rowq = q / 43;
        int e4 = q - rowq * 43;
        int w = rowq >> 10;
        int s = rowq & 1023;
        f4 v;
        if (e4 == 42) {
            v = sm4[s];
        } else {
            int t = w + e4 * 4;
            float lev = levels[s * N_TIME + w + INPUT_SIZE - 1];
            const float* yp = y + s * N_TIME + t;
            const float* sp = seas1 + s * SEAS_LEN + t;
            float vv[4];
#pragma unroll
            for (int j = 0; j < 4; ++j)
                vv[j] = __logf(__fdividef(yp[j], lev * sp[j]));
            v.x = vv[0]; v.y = vv[1]; v.z = vv[2]; v.w = vv[3];
        }
        out_ins[q] = v;
    }
}

extern "C" void kernel_launch(void* const* d_in, const int* in_sizes, int n_in,
                              void* d_out, int out_size, void* d_ws, size_t ws_size,
                              hipStream_t stream) {
    const float* y      = (const float*)d_in[0];
    const float* sm     = (const float*)d_in[1];
    const float* embeds = (const float*)d_in[2];
    const int*   idxs   = (const int*)d_in[3];

    float* out      = (float*)d_out;
    float* out_ins  = out;
    float* out_outs = out + INS_ELEMS;
    float* out_lev  = out + INS_ELEMS + OUTS_ELEMS;
    float* out_seas = out_lev + LEV_ELEMS;

    float* q1raw = (float*)d_ws;
    float* tbl   = q1raw + LEV_ELEMS;
    float* llv   = tbl + LEV_ELEMS;
    const int have_ws = (ws_size >= (size_t)WS_NEEDED) ? 1 : 0;

    scan_copy_kernel<<<SCAN_BLOCKS + COPY_BLOCKS, SCAN_T, 0, stream>>>(
        y, embeds, idxs, out_lev, out_seas, q1raw, (f4*)out_outs, have_ws);
    if (have_ws) {
        logpass_kernel<<<LEV_ELEMS / 4 / 256, 256, 0, stream>>>(
            q1raw, out_lev, tbl, llv);
        ins_kernel<<<COPY_BLOCKS, 256, 0, stream>>>(tbl, llv, sm,
                                                    (f4*)out_ins);
    } else {
        ins_kernel_fb<<<COPY_BLOCKS, 256, 0, stream>>>(y, out_lev, out_seas,
                                                       sm, (f4*)out_ins);
    }
}

// Round 8
// 111.289 us; speedup vs baseline: 2.4153x; 1.0930x over previous
//
#include <hip/hip_runtime.h>

#define N_SERIES 1024
#define N_TIME 600
#define INPUT_SIZE 168
#define OUTPUT_SIZE 24
#define N_S 4
#define SEAS 24
#define N_WINDOWS (N_TIME - INPUT_SIZE - OUTPUT_SIZE + 1) /* 409 */
#define SEAS_LEN (N_TIME + SEAS)                          /* 624 */

#define INS_ELEMS (N_WINDOWS * N_SERIES * (INPUT_SIZE + N_S)) /* 72,036,352 */
#define OUTS_ELEMS (N_WINDOWS * N_SERIES * OUTPUT_SIZE)       /* 10,051,584 */
#define LEV_ELEMS (N_SERIES * N_TIME)
#define SEAS_ELEMS (N_SERIES * SEAS_LEN)

#define NQ_OUTS (OUTS_ELEMS / 4)              /* 2,512,896 */
#define NQ_INS43 (N_WINDOWS * N_SERIES * 43)  /* 18,009,088 */
#define INS_SLICE (NQ_INS43 / 8)              /* 2,251,136 (row-aligned: 43|SLICE) */

#define SCAN_BLOCKS 16
#define SCAN_T 64
#define COPY_BLOCKS 2032
#define INS_BLOCKS 2048
#define WS_NEEDED (2u * LEV_ELEMS * sizeof(float)) /* tbl + llv = 4.9 MB */

typedef float f4 __attribute__((ext_vector_type(4)));

// Single-wave LDS phase fence: LDS ops within one wave retire in order (FIFO
// pipe), so no s_barrier (and no vmcnt drain) is needed — only a compiler
// scheduling fence between the compute (write) and transpose (read) phases.
#define WAVE_FENCE()                                   \
    do {                                               \
        __builtin_amdgcn_wave_barrier();               \
        asm volatile("" ::: "memory");                 \
    } while (0)

// ---------------------------------------------------------------------------
// Kernel 1 (fused):
//   blocks [0,16): exponential-smoothing scan, ONE wave per block. y loaded
//     straight to registers (6 aligned float4/chunk, double-buffered). Per
//     chunk: 24 recurrence steps (registers; ring buffer sb[t%24] with
//     compile-time indices) staging results in LDS, then cooperative f4
//     global stores of levels/seas1. No barriers, no extra tables, no logs.
//   blocks [16,...): outsample window copy (scan-independent).
// ---------------------------------------------------------------------------
__global__ __launch_bounds__(SCAN_T) void scan_copy_kernel(
    const float* __restrict__ y, const float* __restrict__ embeds,
    const int* __restrict__ idxs, float* __restrict__ levels,
    float* __restrict__ seas1, f4* __restrict__ out_outs)
{
    __shared__ float b_lev[SCAN_T][25];
    __shared__ float b_sea[SCAN_T][25];

    if (blockIdx.x < SCAN_BLOCKS) {
        const int lane = threadIdx.x;
        const int s0 = blockIdx.x * SCAN_T;
        const int s = s0 + lane;
        const int row = idxs[s];
        const float* e = embeds + row * (2 + SEAS);

        const float lev_sms = 1.0f / (1.0f + __expf(-e[0]));
        const float seas_sms = 1.0f / (1.0f + __expf(-e[1]));
        const float one_m_lev = 1.0f - lev_sms;
        const float one_m_seas = 1.0f - seas_sms;

        const float* yrow = y + s * N_TIME;
        const f4* yv4 = (const f4*)yrow; // row stride 2400B keeps 16B align

        f4 cur[6], nxt[6];
#pragma unroll
        for (int i = 0; i < 6; ++i) cur[i] = yv4[i];

        float sb[SEAS];
#pragma unroll
        for (int j = 0; j < SEAS; ++j) {
            float v = __expf(e[2 + j]);
            sb[j] = v;
            b_sea[lane][j] = v;
        }
        WAVE_FENCE();
        // init seasonality cols 0..23: cooperative f4 stores (aligned)
#pragma unroll
        for (int k4 = 0; k4 < 6; ++k4) {
            int q4 = lane + k4 * SCAN_T;
            int r = q4 / 6;
            int c4 = q4 - r * 6;
            int cc = c4 * 4;
            f4 v = {b_sea[r][cc], b_sea[r][cc + 1], b_sea[r][cc + 2],
                    b_sea[r][cc + 3]};
            *(f4*)(seas1 + (s0 + r) * SEAS_LEN + cc) = v;
        }
        seas1[s * SEAS_LEN + SEAS] = sb[0]; // col 24 = rolled init_seas[0]
        float lev = __fdividef(cur[0].x, sb[0]);
        levels[s * N_TIME] = lev;
        WAVE_FENCE(); // b_sea reused below

        // ---- chunk 0: t = 1..23 (ring index = t), scalar store path ----
        {
#pragma unroll
            for (int i = 0; i < 6; ++i) nxt[i] = yv4[6 + i];
#pragma unroll
            for (int j = 0; j < 23; ++j) {
                const int t = j + 1;
                float yt = cur[t >> 2][t & 3];
                float st = sb[t];
                float q1 = __fdividef(yt, st);
                float newlev = lev_sms * q1 + one_m_lev * lev;
                float news =
                    seas_sms * __fdividef(yt, newlev) + one_m_seas * st;
                lev = newlev;
                sb[t] = news;
                b_lev[lane][j] = newlev;
                b_sea[lane][j] = news;
            }
            WAVE_FENCE();
#pragma unroll
            for (int k = 0; k < 24; ++k) {
                int i = lane + k * SCAN_T;
                int r = i / 24;
                int col = i - r * 24;
                if (col < 23) {
                    int sr = s0 + r;
                    levels[sr * N_TIME + 1 + col] = b_lev[r][col];
                    seas1[sr * SEAS_LEN + 25 + col] = b_sea[r][col];
                }
            }
            WAVE_FENCE();
#pragma unroll
            for (int i = 0; i < 6; ++i) cur[i] = nxt[i];
        }

        // ---- chunks c = 1..24: t = 24c + j, ring index = j ----
#pragma unroll 1
        for (int c = 1; c < 25; ++c) {
            const int t0 = 24 * c;
            if (c < 24) {
                const f4* p = (const f4*)(yrow + 24 * (c + 1));
#pragma unroll
                for (int i = 0; i < 6; ++i) nxt[i] = p[i];
            }
#pragma unroll
            for (int j = 0; j < 24; ++j) {
                float yt = cur[j >> 2][j & 3];
                float st = sb[j];
                float q1 = __fdividef(yt, st);
                float newlev = lev_sms * q1 + one_m_lev * lev;
                float news =
                    seas_sms * __fdividef(yt, newlev) + one_m_seas * st;
                lev = newlev;
                sb[j] = news;
                b_lev[lane][j] = newlev;
                b_sea[lane][j] = news;
            }
            WAVE_FENCE();
            // cooperative f4 stores: t0 = 24c -> 96c bytes, 16B-aligned
#pragma unroll
            for (int k4 = 0; k4 < 6; ++k4) {
                int q4 = lane + k4 * SCAN_T;
                int r = q4 / 6;
                int c4 = q4 - r * 6;
                int sr = s0 + r;
                int cc = c4 * 4;
                f4 vl = {b_lev[r][cc], b_lev[r][cc + 1], b_lev[r][cc + 2],
                         b_lev[r][cc + 3]};
                *(f4*)(levels + sr * N_TIME + t0 + cc) = vl;
                f4 vs = {b_sea[r][cc], b_sea[r][cc + 1], b_sea[r][cc + 2],
                         b_sea[r][cc + 3]};
                *(f4*)(seas1 + sr * SEAS_LEN + SEAS + t0 + cc) = vs;
            }
            WAVE_FENCE();
#pragma unroll
            for (int i = 0; i < 6; ++i) cur[i] = nxt[i];
        }
    } else {
        // copy role: outsample windows (dense contiguous 40 MB)
        int idx = (blockIdx.x - SCAN_BLOCKS) * SCAN_T + threadIdx.x;
        const int stride = (gridDim.x - SCAN_BLOCKS) * SCAN_T;
        for (; idx < NQ_OUTS; idx += stride) {
            int rowq = idx / 6;
            int j4 = idx - rowq * 6;
            int w = rowq >> 10;
            int s = rowq & 1023;
            const float* yp = y + s * N_TIME + w + INPUT_SIZE + j4 * 4;
            f4 v = {yp[0], yp[1], yp[2], yp[3]};
            out_outs[idx] = v;
        }
    }
}

// ---------------------------------------------------------------------------
// Kernel 2: full-GPU parallel log pass from y + d_out tables:
//   tbl[s][t] = log(y/seas1), llv[s][t] = log(levels). 600 blocks, ~3 us.
// ---------------------------------------------------------------------------
__global__ __launch_bounds__(256) void logpass_kernel(
    const float* __restrict__ y, const float* __restrict__ levels,
    const float* __restrict__ seas1, float* __restrict__ tbl,
    float* __restrict__ llv)
{
    int i = blockIdx.x * 256 + threadIdx.x; // f4 index over [0, 153600)
    int sr = i / 150;
    int c = i - sr * 150;
    f4 a = *((const f4*)(y + sr * N_TIME) + c);
    f4 se = *((const f4*)(seas1 + sr * SEAS_LEN) + c); // 2496B rows, aligned
    f4 l = *((const f4*)(levels + sr * N_TIME) + c);
    f4 ta, tl;
    ta.x = __logf(__fdividef(a.x, se.x));
    ta.y = __logf(__fdividef(a.y, se.y));
    ta.z = __logf(__fdividef(a.z, se.z));
    ta.w = __logf(__fdividef(a.w, se.w));
    tl.x = __logf(l.x);
    tl.y = __logf(l.y);
    tl.z = __logf(l.z);
    tl.w = __logf(l.w);
    ((f4*)tbl)[i] = ta;
    ((f4*)llv)[i] = tl;
}

// ---------------------------------------------------------------------------
// Kernel 3 (fast path, UNCHANGED from R7): insample rows incl. static column.
// XCD-clustered q mapping: block b -> xcd b&7 owns a contiguous 1/8 q-slice.
// ---------------------------------------------------------------------------
__global__ __launch_bounds__(256) void ins_kernel(
    const float* __restrict__ tbl, const float* __restrict__ llv,
    const float* __restrict__ s_matrix, f4* __restrict__ out_ins)
{
    const f4* sm4 = (const f4*)s_matrix;
    const int xcd = blockIdx.x & 7;
    const int lb = blockIdx.x >> 3; // 0..255
    const int qend = (xcd + 1) * INS_SLICE;
    const int stride = (INS_BLOCKS / 8) * 256; /* 65536 */
    for (int q = xcd * INS_SLICE + lb * 256 + (int)threadIdx.x; q < qend;
         q += stride) {
        int rowq = q / 43;
        int e4 = q - rowq * 43;
        int w = rowq >> 10;
        int s = rowq & 1023;
        f4 v;
        if (e4 == 42) {
            v = sm4[s];
        } else {
            int t = w + e4 * 4;
            const float* tp = tbl + s * N_TIME + t;
            float lv = llv[s * N_TIME + w + INPUT_SIZE - 1];
            v.x = tp[0] - lv;
            v.y = tp[1] - lv;
            v.z = tp[2] - lv;
            v.w = tp[3] - lv;
        }
        out_ins[q] = v;
    }
}

// Fallback (ws too small): compute logs on the fly, same XCD clustering.
__global__ __launch_bounds__(256) void ins_kernel_fb(
    const float* __restrict__ y, const float* __restrict__ levels,
    const float* __restrict__ seas1, const float* __restrict__ s_matrix,
    f4* __restrict__ out_ins)
{
    const f4* sm4 = (const f4*)s_matrix;
    const int xcd = blockIdx.x & 7;
    const int lb = blockIdx.x >> 3;
    const int qend = (xcd + 1) * INS_SLICE;
    const int stride = (INS_BLOCKS / 8) * 256;
    for (int q = xcd * INS_SLICE + lb * 256 + (int)threadIdx.x; q < qend;
         q += stride) {
        int rowq = q / 43;
        int e4 = q - rowq * 43;
        int w = rowq >> 10;
        int s = rowq & 1023;
        f4 v;
        if (e4 == 42) {
            v = sm4[s];
        } else {
            int t = w + e4 * 4;
            float lev = levels[s * N_TIME + w + INPUT_SIZE - 1];
            const float* yp = y + s * N_TIME + t;
            const float* sp = seas1 + s * SEAS_LEN + t;
            float vv[4];
#pragma unroll
            for (int j = 0; j < 4; ++j)
                vv[j] = __logf(__fdividef(yp[j], lev * sp[j]));
            v.x = vv[0]; v.y = vv[1]; v.z = vv[2]; v.w = vv[3];
        }
        out_ins[q] = v;
    }
}

extern "C" void kernel_launch(void* const* d_in, const int* in_sizes, int n_in,
                              void* d_out, int out_size, void* d_ws, size_t ws_size,
                              hipStream_t stream) {
    const float* y      = (const float*)d_in[0];
    const float* sm     = (const float*)d_in[1];
    const float* embeds = (const float*)d_in[2];
    const int*   idxs   = (const int*)d_in[3];

    float* out      = (float*)d_out;
    float* out_ins  = out;
    float* out_outs = out + INS_ELEMS;
    float* out_lev  = out + INS_ELEMS + OUTS_ELEMS;
    float* out_seas = out_lev + LEV_ELEMS;

    float* tbl = (float*)d_ws;
    float* llv = tbl + LEV_ELEMS;
    const int have_ws = (ws_size >= (size_t)WS_NEEDED) ? 1 : 0;

    scan_copy_kernel<<<SCAN_BLOCKS + COPY_BLOCKS, SCAN_T, 0, stream>>>(
        y, embeds, idxs, out_lev, out_seas, (f4*)out_outs);
    if (have_ws) {
        logpass_kernel<<<LEV_ELEMS / 4 / 256, 256, 0, stream>>>(
            y, out_lev, out_seas, tbl, llv);
        ins_kernel<<<INS_BLOCKS, 256, 0, stream>>>(tbl, llv, sm,
                                                   (f4*)out_ins);
    } else {
        ins_kernel_fb<<<INS_BLOCKS, 256, 0, stream>>>(y, out_lev, out_seas,
                                                      sm, (f4*)out_ins);
    }
}

// Round 9
// 108.560 us; speedup vs baseline: 2.4760x; 1.0251x over previous
//
#include <hip/hip_runtime.h>

#define N_SERIES 1024
#define N_TIME 600
#define INPUT_SIZE 168
#define OUTPUT_SIZE 24
#define N_S 4
#define SEAS 24
#define N_WINDOWS (N_TIME - INPUT_SIZE - OUTPUT_SIZE + 1) /* 409 */
#define SEAS_LEN (N_TIME + SEAS)                          /* 624 */

#define INS_ELEMS (N_WINDOWS * N_SERIES * (INPUT_SIZE + N_S)) /* 72,036,352 */
#define OUTS_ELEMS (N_WINDOWS * N_SERIES * OUTPUT_SIZE)       /* 10,051,584 */
#define LEV_ELEMS (N_SERIES * N_TIME)
#define SEAS_ELEMS (N_SERIES * SEAS_LEN)

#define NQ_OUTS (OUTS_ELEMS / 4)              /* 2,512,896 */
#define NQ_INS43 (N_WINDOWS * N_SERIES * 43)  /* 18,009,088 */
#define INS_SLICE (NQ_INS43 / 8)              /* 2,251,136 (43|SLICE, 64|SLICE) */

#define SCAN_BLOCKS 16
#define SCAN_T 64
#define COPY_BLOCKS 2032
#define INS_BLOCKS 2048
#define WS_NEEDED (2u * LEV_ELEMS * sizeof(float)) /* tbl + llv = 4.9 MB */

typedef float f4 __attribute__((ext_vector_type(4)));

// Single-wave LDS phase fence: LDS ops within one wave retire in order, so no
// s_barrier / vmcnt drain — only a compiler scheduling fence between phases.
#define WAVE_FENCE()                                   \
    do {                                               \
        __builtin_amdgcn_wave_barrier();               \
        asm volatile("" ::: "memory");                 \
    } while (0)

// ---------------------------------------------------------------------------
// Kernel 1 (fused):
//   blocks [0,16): exponential-smoothing scan, ONE wave per block (R8 body).
//   blocks [16,...): outsample window copy — dense wave-aligned 1KB writes,
//     now NONTEMPORAL (no partial lines: NQ_OUTS base 64-q aligned).
// ---------------------------------------------------------------------------
__global__ __launch_bounds__(SCAN_T) void scan_copy_kernel(
    const float* __restrict__ y, const float* __restrict__ embeds,
    const int* __restrict__ idxs, float* __restrict__ levels,
    float* __restrict__ seas1, f4* __restrict__ out_outs)
{
    __shared__ float b_lev[SCAN_T][25];
    __shared__ float b_sea[SCAN_T][25];

    if (blockIdx.x < SCAN_BLOCKS) {
        const int lane = threadIdx.x;
        const int s0 = blockIdx.x * SCAN_T;
        const int s = s0 + lane;
        const int row = idxs[s];
        const float* e = embeds + row * (2 + SEAS);

        const float lev_sms = 1.0f / (1.0f + __expf(-e[0]));
        const float seas_sms = 1.0f / (1.0f + __expf(-e[1]));
        const float one_m_lev = 1.0f - lev_sms;
        const float one_m_seas = 1.0f - seas_sms;

        const float* yrow = y + s * N_TIME;
        const f4* yv4 = (const f4*)yrow; // row stride 2400B keeps 16B align

        f4 cur[6], nxt[6];
#pragma unroll
        for (int i = 0; i < 6; ++i) cur[i] = yv4[i];

        float sb[SEAS];
#pragma unroll
        for (int j = 0; j < SEAS; ++j) {
            float v = __expf(e[2 + j]);
            sb[j] = v;
            b_sea[lane][j] = v;
        }
        WAVE_FENCE();
        // init seasonality cols 0..23: cooperative f4 stores (aligned)
#pragma unroll
        for (int k4 = 0; k4 < 6; ++k4) {
            int q4 = lane + k4 * SCAN_T;
            int r = q4 / 6;
            int c4 = q4 - r * 6;
            int cc = c4 * 4;
            f4 v = {b_sea[r][cc], b_sea[r][cc + 1], b_sea[r][cc + 2],
                    b_sea[r][cc + 3]};
            *(f4*)(seas1 + (s0 + r) * SEAS_LEN + cc) = v;
        }
        seas1[s * SEAS_LEN + SEAS] = sb[0]; // col 24 = rolled init_seas[0]
        float lev = __fdividef(cur[0].x, sb[0]);
        levels[s * N_TIME] = lev;
        WAVE_FENCE(); // b_sea reused below

        // ---- chunk 0: t = 1..23 (ring index = t), scalar store path ----
        {
#pragma unroll
            for (int i = 0; i < 6; ++i) nxt[i] = yv4[6 + i];
#pragma unroll
            for (int j = 0; j < 23; ++j) {
                const int t = j + 1;
                float yt = cur[t >> 2][t & 3];
                float st = sb[t];
                float q1 = __fdividef(yt, st);
                float newlev = lev_sms * q1 + one_m_lev * lev;
                float news =
                    seas_sms * __fdividef(yt, newlev) + one_m_seas * st;
                lev = newlev;
                sb[t] = news;
                b_lev[lane][j] = newlev;
                b_sea[lane][j] = news;
            }
            WAVE_FENCE();
#pragma unroll
            for (int k = 0; k < 24; ++k) {
                int i = lane + k * SCAN_T;
                int r = i / 24;
                int col = i - r * 24;
                if (col < 23) {
                    int sr = s0 + r;
                    levels[sr * N_TIME + 1 + col] = b_lev[r][col];
                    seas1[sr * SEAS_LEN + 25 + col] = b_sea[r][col];
                }
            }
            WAVE_FENCE();
#pragma unroll
            for (int i = 0; i < 6; ++i) cur[i] = nxt[i];
        }

        // ---- chunks c = 1..24: t = 24c + j, ring index = j ----
#pragma unroll 1
        for (int c = 1; c < 25; ++c) {
            const int t0 = 24 * c;
            if (c < 24) {
                const f4* p = (const f4*)(yrow + 24 * (c + 1));
#pragma unroll
                for (int i = 0; i < 6; ++i) nxt[i] = p[i];
            }
#pragma unroll
            for (int j = 0; j < 24; ++j) {
                float yt = cur[j >> 2][j & 3];
                float st = sb[j];
                float q1 = __fdividef(yt, st);
                float newlev = lev_sms * q1 + one_m_lev * lev;
                float news =
                    seas_sms * __fdividef(yt, newlev) + one_m_seas * st;
                lev = newlev;
                sb[j] = news;
                b_lev[lane][j] = newlev;
                b_sea[lane][j] = news;
            }
            WAVE_FENCE();
            // cooperative f4 stores: t0 = 24c -> 96c bytes, 16B-aligned
#pragma unroll
            for (int k4 = 0; k4 < 6; ++k4) {
                int q4 = lane + k4 * SCAN_T;
                int r = q4 / 6;
                int c4 = q4 - r * 6;
                int sr = s0 + r;
                int cc = c4 * 4;
                f4 vl = {b_lev[r][cc], b_lev[r][cc + 1], b_lev[r][cc + 2],
                         b_lev[r][cc + 3]};
                *(f4*)(levels + sr * N_TIME + t0 + cc) = vl;
                f4 vs = {b_sea[r][cc], b_sea[r][cc + 1], b_sea[r][cc + 2],
                         b_sea[r][cc + 3]};
                *(f4*)(seas1 + sr * SEAS_LEN + SEAS + t0 + cc) = vs;
            }
            WAVE_FENCE();
#pragma unroll
            for (int i = 0; i < 6; ++i) cur[i] = nxt[i];
        }
    } else {
        // copy role: outsample windows — dense wave-aligned, nontemporal
        int idx = (blockIdx.x - SCAN_BLOCKS) * SCAN_T + threadIdx.x;
        const int stride = (gridDim.x - SCAN_BLOCKS) * SCAN_T;
        for (; idx < NQ_OUTS; idx += stride) {
            int rowq = idx / 6;
            int j4 = idx - rowq * 6;
            int w = rowq >> 10;
            int s = rowq & 1023;
            const float* yp = y + s * N_TIME + w + INPUT_SIZE + j4 * 4;
            f4 v = {yp[0], yp[1], yp[2], yp[3]};
            __builtin_nontemporal_store(v, &out_outs[idx]);
        }
    }
}

// ---------------------------------------------------------------------------
// Kernel 2: full-GPU parallel log pass from y + d_out tables:
//   tbl[s][t] = log(y/seas1), llv[s][t] = log(levels). Cached stores (read
//   immediately by ins_kernel).
// ---------------------------------------------------------------------------
__global__ __launch_bounds__(256) void logpass_kernel(
    const float* __restrict__ y, const float* __restrict__ levels,
    const float* __restrict__ seas1, float* __restrict__ tbl,
    float* __restrict__ llv)
{
    int i = blockIdx.x * 256 + threadIdx.x; // f4 index over [0, 153600)
    int sr = i / 150;
    int c = i - sr * 150;
    f4 a = *((const f4*)(y + sr * N_TIME) + c);
    f4 se = *((const f4*)(seas1 + sr * SEAS_LEN) + c); // 2496B rows, aligned
    f4 l = *((const f4*)(levels + sr * N_TIME) + c);
    f4 ta, tl;
    ta.x = __logf(__fdividef(a.x, se.x));
    ta.y = __logf(__fdividef(a.y, se.y));
    ta.z = __logf(__fdividef(a.z, se.z));
    ta.w = __logf(__fdividef(a.w, se.w));
    tl.x = __logf(l.x);
    tl.y = __logf(l.y);
    tl.z = __logf(l.z);
    tl.w = __logf(l.w);
    ((f4*)tbl)[i] = ta;
    ((f4*)llv)[i] = tl;
}

// ---------------------------------------------------------------------------
// Kernel 3 (fast path): insample rows incl. static column. XCD-clustered
// 1/8 q-slices (L2-resident reads). NONTEMPORAL stores: every wave writes a
// 64-aligned run of 64 q's = 16 full cache lines (INS_SLICE, 256, 64 all
// ≡ 0 mod 64, slice tails exact waves) -> no partial lines, no L2
// write-allocate thrash. Incremental rowq/e4 (65536 = 43*1524 + 4).
// ---------------------------------------------------------------------------
__global__ __launch_bounds__(256) void ins_kernel(
    const float* __restrict__ tbl, const float* __restrict__ llv,
    const float* __restrict__ s_matrix, f4* __restrict__ out_ins)
{
    const f4* sm4 = (const f4*)s_matrix;
    const int xcd = blockIdx.x & 7;
    const int lb = blockIdx.x >> 3; // 0..255
    const int qend = (xcd + 1) * INS_SLICE;
    const int stride = (INS_BLOCKS / 8) * 256; /* 65536 */
    int q = xcd * INS_SLICE + lb * 256 + (int)threadIdx.x;
    int rowq = q / 43;
    int e4 = q - rowq * 43;
    for (; q < qend; q += stride) {
        int w = rowq >> 10;
        int s = rowq & 1023;
        f4 v;
        if (e4 == 42) {
            v = sm4[s];
        } else {
            int t = w + e4 * 4;
            const float* tp = tbl + s * N_TIME + t;
            float lv = llv[s * N_TIME + w + INPUT_SIZE - 1];
            v.x = tp[0] - lv;
            v.y = tp[1] - lv;
            v.z = tp[2] - lv;
            v.w = tp[3] - lv;
        }
        __builtin_nontemporal_store(v, &out_ins[q]);
        rowq += 1524;
        e4 += 4;
        if (e4 >= 43) {
            e4 -= 43;
            rowq += 1;
        }
    }
}

// Fallback (ws too small): compute logs on the fly, same XCD clustering.
__global__ __launch_bounds__(256) void ins_kernel_fb(
    const float* __restrict__ y, const float* __restrict__ levels,
    const float* __restrict__ seas1, const float* __restrict__ s_matrix,
    f4* __restrict__ out_ins)
{
    const f4* sm4 = (const f4*)s_matrix;
    const int xcd = blockIdx.x & 7;
    const int lb = blockIdx.x >> 3;
    const int qend = (xcd + 1) * INS_SLICE;
    const int stride = (INS_BLOCKS / 8) * 256;
    for (int q = xcd * INS_SLICE + lb * 256 + (int)threadIdx.x; q < qend;
         q += stride) {
        int rowq = q / 43;
        int e4 = q - rowq * 43;
        int w = rowq >> 10;
        int s = rowq & 1023;
        f4 v;
        if (e4 == 42) {
            v = sm4[s];
        } else {
            int t = w + e4 * 4;
            float lev = levels[s * N_TIME + w + INPUT_SIZE - 1];
            const float* yp = y + s * N_TIME + t;
            const float* sp = seas1 + s * SEAS_LEN + t;
            float vv[4];
#pragma unroll
            for (int j = 0; j < 4; ++j)
                vv[j] = __logf(__fdividef(yp[j], lev * sp[j]));
            v.x = vv[0]; v.y = vv[1]; v.z = vv[2]; v.w = vv[3];
        }
        __builtin_nontemporal_store(v, &out_ins[q]);
    }
}

extern "C" void kernel_launch(void* const* d_in, const int* in_sizes, int n_in,
                              void* d_out, int out_size, void* d_ws, size_t ws_size,
                              hipStream_t stream) {
    const float* y      = (const float*)d_in[0];
    const float* sm     = (const float*)d_in[1];
    const float* embeds = (const float*)d_in[2];
    const int*   idxs   = (const int*)d_in[3];

    float* out      = (float*)d_out;
    float* out_ins  = out;
    float* out_outs = out + INS_ELEMS;
    float* out_lev  = out + INS_ELEMS + OUTS_ELEMS;
    float* out_seas = out_lev + LEV_ELEMS;

    float* tbl = (float*)d_ws;
    float* llv = tbl + LEV_ELEMS;
    const int have_ws = (ws_size >= (size_t)WS_NEEDED) ? 1 : 0;

    scan_copy_kernel<<<SCAN_BLOCKS + COPY_BLOCKS, SCAN_T, 0, stream>>>(
        y, embeds, idxs, out_lev, out_seas, (f4*)out_outs);
    if (have_ws) {
        logpass_kernel<<<LEV_ELEMS / 4 / 256, 256, 0, stream>>>(
            y, out_lev, out_seas, tbl, llv);
        ins_kernel<<<INS_BLOCKS, 256, 0, stream>>>(tbl, llv, sm,
                                                   (f4*)out_ins);
    } else {
        ins_kernel_fb<<<INS_BLOCKS, 256, 0, stream>>>(y, out_lev, out_seas,
                                                      sm, (f4*)out_ins);
    }
}